// Round 5
// baseline (4076.194 us; speedup 1.0000x reference)
//
#include <hip/hip_runtime.h>

typedef _Float16 h2f __attribute__((ext_vector_type(2)));
typedef _Float16 f16x8 __attribute__((ext_vector_type(8)));
typedef float f32x4 __attribute__((ext_vector_type(4)));
typedef unsigned int u32;
typedef unsigned short u16;

#define B_ 128
#define S_ 1024
#define I_ 256
#define H_ 512
#define O_ 256
#define IH_ 768

#if __has_builtin(__builtin_amdgcn_fdot2)
__device__ __forceinline__ float fdot2u(u32 a, u32 b, float c) {
    return __builtin_amdgcn_fdot2(__builtin_bit_cast(h2f, a),
                                  __builtin_bit_cast(h2f, b), c, false);
}
#else
__device__ __forceinline__ float fdot2u(u32 a, u32 b, float c) {
    h2f av = __builtin_bit_cast(h2f, a), bv = __builtin_bit_cast(h2f, b);
    return c + (float)av.x * (float)bv.x + (float)av.y * (float)bv.y;
}
#endif

__device__ __forceinline__ u32 pack2(float x, float y) {
    return __builtin_bit_cast(u32, __builtin_amdgcn_cvt_pkrtz(x, y));
}
__device__ __forceinline__ u16 f2h(float x) { return __builtin_bit_cast(u16, (_Float16)x); }
__device__ __forceinline__ float h2f_(u16 x) { return (float)__builtin_bit_cast(_Float16, x); }

__device__ __forceinline__ float tanh_fast(float x) {
    float e = __expf(-2.f * fabsf(x));     // e in (0,1] -- no overflow path
    float r = (1.f - e) / (1.f + e);
    return copysignf(r, x);
}

// MFMA: D = A(16x32)*B(32x16)+C, f16 in / f32 acc.
// Verified layouts (m89/m91): A[m=lane&15][k=(lane>>4)*8+j],
// B[k=(lane>>4)*8+j][n=lane&15], C/D col=lane&15 row=(lane>>4)*4+reg.
__device__ __forceinline__ f32x4 mfx(uint4 a, uint4 b, f32x4 c) {
    return __builtin_amdgcn_mfma_f32_16x16x32_f16(
        __builtin_bit_cast(f16x8, a), __builtin_bit_cast(f16x8, b), c, 0, 0, 0);
}
__device__ __forceinline__ f32x4 mf(uint4 a, const uint4* bp, f32x4 c) {
    uint4 b = *bp;
    return mfx(a, b, c);
}

#define REP8(X)  X(0) X(1) X(2) X(3) X(4) X(5) X(6) X(7)
#define REP16(X) REP8(X) X(8) X(9) X(10) X(11) X(12) X(13) X(14) X(15)
#define REPK11(X) X(0) X(1) X(2) X(3) X(4) X(5) X(6) X(7) X(8) X(9) X(10)

// ---------------------------------------------------------------------------
// Workspace layout (bytes):
//   wxb4 @ 0      : 16384 uint4 (256 KB)  Wx octets [q 0..31][col 0..511]
//                   octet q of col c = W[c][q*8 .. q*8+7] as f16
//   whb4 @ 256 KB : 32768 uint4 (512 KB)  Wh octets [q 0..63][n 0..511]
//                   octet q of col n = W[n][256+q*8 .. +7] as f16
//   pre  @ 1 MB   : 128*1024*512 f16 (128 MB)
// ---------------------------------------------------------------------------
#define WXB_OFF 0
#define WHB_OFF (256u << 10)
#define PRE_OFF (1u << 20)

__global__ __launch_bounds__(256) void k_convert(const float* __restrict__ W,
                                                 uint4* __restrict__ wxb4,
                                                 uint4* __restrict__ whb4) {
    int idx = blockIdx.x * 256 + threadIdx.x;       // 0..49151
    if (idx < 16384) {                               // wxb: q = idx>>9 (0..31)
        int q = idx >> 9, col = idx & 511;
        const float4* r = (const float4*)(W + (long)col * IH_ + q * 8);
        float4 u = r[0], v = r[1];
        wxb4[idx] = (uint4){pack2(u.x, u.y), pack2(u.z, u.w),
                            pack2(v.x, v.y), pack2(v.z, v.w)};
    } else {                                         // whb: q = 0..63
        int i2 = idx - 16384;
        int q = i2 >> 9, n = i2 & 511;
        const float4* r = (const float4*)(W + (long)n * IH_ + I_ + q * 8);
        float4 u = r[0], v = r[1];
        whb4[i2] = (uint4){pack2(u.x, u.y), pack2(u.z, u.w),
                           pack2(v.x, v.y), pack2(v.z, v.w)};
    }
}

// ---------------------------------------------------------------------------
// Phase 1 (MFMA GEMM, ~40 us -- unchanged):
// pre[r][j] = b_i2h[j] + sum_i x[r][i]*Wx[i][j], f16 out.
// ---------------------------------------------------------------------------
__global__ __launch_bounds__(256) __attribute__((amdgpu_waves_per_eu(2, 2)))
void k_phase1(const float* __restrict__ seq, const uint4* __restrict__ wxb4,
              const float* __restrict__ bias, u16* __restrict__ pre) {
    int w = threadIdx.x >> 6, l = threadIdx.x & 63;
    int lm = l & 15, lq = l >> 4;
    int mb_w = blockIdx.x * 64 + w * 16;
    long xrow = (long)(mb_w + lm) * I_;
#define DECLA1(k) uint4 a##k; { \
        const float4* xp = (const float4*)(seq + xrow + (k)*32 + lq*8); \
        float4 u = xp[0], v = xp[1]; \
        a##k = (uint4){pack2(u.x,u.y), pack2(u.z,u.w), pack2(v.x,v.y), pack2(v.z,v.w)}; }
    REP8(DECLA1)
#undef DECLA1
    int mrow0 = mb_w + lq * 4;
#pragma unroll
    for (int half = 0; half < 2; ++half) {
        int colbase = half * 256;
        const uint4* bptr = wxb4 + colbase + lm;
#define DECLC(n) float bv##n = bias[colbase + (n)*16 + lm]; \
                 f32x4 c##n = {bv##n, bv##n, bv##n, bv##n};
        REP16(DECLC)
#undef DECLC
#define ROW(k,n) c##n = mf(a##k, bptr + ((k)*4 + lq)*512 + (n)*16, c##n);
#define KS(k) ROW(k,0) ROW(k,1) ROW(k,2) ROW(k,3) ROW(k,4) ROW(k,5) ROW(k,6) ROW(k,7) \
              ROW(k,8) ROW(k,9) ROW(k,10) ROW(k,11) ROW(k,12) ROW(k,13) ROW(k,14) ROW(k,15)
        KS(0) KS(1) KS(2) KS(3) KS(4) KS(5) KS(6) KS(7)
#undef KS
#undef ROW
#define STN(n) { long cb = (long)colbase + (n)*16 + lm; \
        pre[(long)(mrow0+0)*H_ + cb] = f2h(c##n[0]); \
        pre[(long)(mrow0+1)*H_ + cb] = f2h(c##n[1]); \
        pre[(long)(mrow0+2)*H_ + cb] = f2h(c##n[2]); \
        pre[(long)(mrow0+3)*H_ + cb] = f2h(c##n[3]); }
        REP16(STN)
#undef STN
    }
}

// ---------------------------------------------------------------------------
// Phase 2 v5: fat-wave MFMA recurrence. One WG = 256 thr = 4 waves =
// 1 wave/SIMD (waves_per_eu(1,1) -> 512-reg budget/thread).
// Wave w owns cols 128w..128w+127 as 8 col-groups g (16 cols each):
//   acc_g = C-init(pre); for K=0..15: acc_g = mfma(A_K, B_{K,g}, acc_g)
// A_K[m][k] = h[32K+k] broadcast over rows (result rows all equal).
// Why fewer/fatter waves: CU regfile (512 KB) == sizeof(Wh); per-wave
// overheads (acc/A/stream bufs) are paid per wave, and A-broadcast
// expansion costs 16 KB LDS traffic per wave. 4 waves x 512 regs gives
// B-residency 352 regs/thread (vs 160) and halves A-traffic:
// per-CU-step LDS drops 256 KB -> 160 KB (the measured bottleneck pipe).
// Fragment residency (16 K-steps x 8 groups = 128 frags/thread):
//   K  0..10 : 88 resident uint4 (352 regs)
//   K 11..13 : LDS slabs q=44..55 (96 KB static, filled once)
//   K 14..15 : streamed from L2 each step (16 frags, 64 KB/step/WG)
// MFMA/SIMD/step unchanged (128); 8 independent acc chains/wave = ILP
// to saturate the pipe from one wave. One barrier per step.
// ---------------------------------------------------------------------------
__global__ __launch_bounds__(256) __attribute__((amdgpu_waves_per_eu(1, 1)))
void k_phase2(const u16* __restrict__ pre, const uint4* __restrict__ whb4,
              const float* __restrict__ Who, const float* __restrict__ bo,
              float* __restrict__ out) {
    __shared__ __align__(16) uint4 wlds[12 * 512];  // 96 KB, slabs q=44..55
    __shared__ __align__(16) u16 hbuf[2][H_];
    int b = blockIdx.x, t_ = threadIdx.x;
    int w = t_ >> 6, lane = t_ & 63;
    int n_ = lane & 15, gq = lane >> 4;             // col-in-group, k-subrow
    int colbase = w * 128;
    int cb0 = colbase,      cb1 = colbase + 16,  cb2 = colbase + 32,  cb3 = colbase + 48;
    int cb4 = colbase + 64, cb5 = colbase + 80,  cb6 = colbase + 96,  cb7 = colbase + 112;
    // resident B-fragments, K = 0..10 (88 x uint4 = 352 regs)
#define DECLB(K) \
    uint4 b##K##_0 = whb4[(4*(K) + gq) * 512 + cb0 + n_]; \
    uint4 b##K##_1 = whb4[(4*(K) + gq) * 512 + cb1 + n_]; \
    uint4 b##K##_2 = whb4[(4*(K) + gq) * 512 + cb2 + n_]; \
    uint4 b##K##_3 = whb4[(4*(K) + gq) * 512 + cb3 + n_]; \
    uint4 b##K##_4 = whb4[(4*(K) + gq) * 512 + cb4 + n_]; \
    uint4 b##K##_5 = whb4[(4*(K) + gq) * 512 + cb5 + n_]; \
    uint4 b##K##_6 = whb4[(4*(K) + gq) * 512 + cb6 + n_]; \
    uint4 b##K##_7 = whb4[(4*(K) + gq) * 512 + cb7 + n_];
    REPK11(DECLB)
#undef DECLB
#pragma unroll
    for (int s_ = 0; s_ < 24; ++s_) wlds[s_ * 256 + t_] = whb4[44 * 512 + s_ * 256 + t_];
    // pre pointer: thread needs cols cb{g} + n_ each step (C-init values)
    const u16* pr = pre + (long)b * S_ * H_ + colbase + n_;
    hbuf[0][t_] = 0;                                // h_{-1} = 0
    hbuf[0][t_ + 256] = 0;
    __syncthreads();
    u16 pv0 = pr[0],  pv1 = pr[16], pv2 = pr[32],  pv3 = pr[48];
    u16 pv4 = pr[64], pv5 = pr[80], pv6 = pr[96],  pv7 = pr[112];
    for (int t = 0; t < S_; ++t) {
        int cur = t & 1, nxt = cur ^ 1;
        long tn = (t + 1 < S_) ? (long)(t + 1) : (long)t;
        int zoff = 0, lz = 0;
        asm volatile("" : "+v"(zoff), "+v"(lz));    // block LICM of weight loads
        // streamed B-fragments (K=14 first chunk; K=15 issued mid-loop)
#define SLOADK(K) \
        uint4 s##K##_0 = whb4[(4*(K) + gq) * 512 + cb0 + n_ + zoff]; \
        uint4 s##K##_1 = whb4[(4*(K) + gq) * 512 + cb1 + n_ + zoff]; \
        uint4 s##K##_2 = whb4[(4*(K) + gq) * 512 + cb2 + n_ + zoff]; \
        uint4 s##K##_3 = whb4[(4*(K) + gq) * 512 + cb3 + n_ + zoff]; \
        uint4 s##K##_4 = whb4[(4*(K) + gq) * 512 + cb4 + n_ + zoff]; \
        uint4 s##K##_5 = whb4[(4*(K) + gq) * 512 + cb5 + n_ + zoff]; \
        uint4 s##K##_6 = whb4[(4*(K) + gq) * 512 + cb6 + n_ + zoff]; \
        uint4 s##K##_7 = whb4[(4*(K) + gq) * 512 + cb7 + n_ + zoff];
        SLOADK(14)
        u16 pn0 = pr[tn * H_ +  0], pn1 = pr[tn * H_ + 16];
        u16 pn2 = pr[tn * H_ + 32], pn3 = pr[tn * H_ + 48];
        u16 pn4 = pr[tn * H_ + 64], pn5 = pr[tn * H_ + 80];
        u16 pn6 = pr[tn * H_ + 96], pn7 = pr[tn * H_ + 112];
        const u16* hc = hbuf[cur];
        // A-fragments: A_K = h[32K..32K+31] broadcast; lane reads 16B at
        // 64K + 16*gq bytes (uniform per 16-lane group -> LDS broadcast)
#define DECLA(K) uint4 a##K = *(const uint4*)(hc + 32*(K) + 8*gq);
        // LDS B-fragments, K = 11..13
#define LB(K) \
        uint4 l##K##_0 = wlds[(4*((K)-11) + gq) * 512 + cb0 + n_ + lz]; \
        uint4 l##K##_1 = wlds[(4*((K)-11) + gq) * 512 + cb1 + n_ + lz]; \
        uint4 l##K##_2 = wlds[(4*((K)-11) + gq) * 512 + cb2 + n_ + lz]; \
        uint4 l##K##_3 = wlds[(4*((K)-11) + gq) * 512 + cb3 + n_ + lz]; \
        uint4 l##K##_4 = wlds[(4*((K)-11) + gq) * 512 + cb4 + n_ + lz]; \
        uint4 l##K##_5 = wlds[(4*((K)-11) + gq) * 512 + cb5 + n_ + lz]; \
        uint4 l##K##_6 = wlds[(4*((K)-11) + gq) * 512 + cb6 + n_ + lz]; \
        uint4 l##K##_7 = wlds[(4*((K)-11) + gq) * 512 + cb7 + n_ + lz];
#define MK8R(K) \
        c0 = mfx(a##K, b##K##_0, c0); c1 = mfx(a##K, b##K##_1, c1); \
        c2 = mfx(a##K, b##K##_2, c2); c3 = mfx(a##K, b##K##_3, c3); \
        c4 = mfx(a##K, b##K##_4, c4); c5 = mfx(a##K, b##K##_5, c5); \
        c6 = mfx(a##K, b##K##_6, c6); c7 = mfx(a##K, b##K##_7, c7);
#define MK8L(K) \
        c0 = mfx(a##K, l##K##_0, c0); c1 = mfx(a##K, l##K##_1, c1); \
        c2 = mfx(a##K, l##K##_2, c2); c3 = mfx(a##K, l##K##_3, c3); \
        c4 = mfx(a##K, l##K##_4, c4); c5 = mfx(a##K, l##K##_5, c5); \
        c6 = mfx(a##K, l##K##_6, c6); c7 = mfx(a##K, l##K##_7, c7);
#define MK8S(K) \
        c0 = mfx(a##K, s##K##_0, c0); c1 = mfx(a##K, s##K##_1, c1); \
        c2 = mfx(a##K, s##K##_2, c2); c3 = mfx(a##K, s##K##_3, c3); \
        c4 = mfx(a##K, s##K##_4, c4); c5 = mfx(a##K, s##K##_5, c5); \
        c6 = mfx(a##K, s##K##_6, c6); c7 = mfx(a##K, s##K##_7, c7);
        float p0f = h2f_(pv0), p1f = h2f_(pv1), p2f = h2f_(pv2), p3f = h2f_(pv3);
        float p4f = h2f_(pv4), p5f = h2f_(pv5), p6f = h2f_(pv6), p7f = h2f_(pv7);
        f32x4 c0 = {p0f, p0f, p0f, p0f};
        f32x4 c1 = {p1f, p1f, p1f, p1f};
        f32x4 c2 = {p2f, p2f, p2f, p2f};
        f32x4 c3 = {p3f, p3f, p3f, p3f};
        f32x4 c4 = {p4f, p4f, p4f, p4f};
        f32x4 c5 = {p5f, p5f, p5f, p5f};
        f32x4 c6 = {p6f, p6f, p6f, p6f};
        f32x4 c7 = {p7f, p7f, p7f, p7f};
        DECLA(0) DECLA(1)
        MK8R(0)
        DECLA(2)
        MK8R(1)
        DECLA(3)
        MK8R(2)
        DECLA(4)
        MK8R(3)
        DECLA(5)
        MK8R(4)
        SLOADK(15)
        DECLA(6)
        MK8R(5)
        DECLA(7)
        MK8R(6)
        LB(11)
        DECLA(8)
        MK8R(7)
        DECLA(9)
        MK8R(8)
        LB(12)
        DECLA(10)
        MK8R(9)
        DECLA(11)
        MK8R(10)
        LB(13)
        DECLA(12) DECLA(13)
        MK8L(11)
        DECLA(14)
        MK8L(12)
        DECLA(15)
        MK8L(13)
        MK8S(14)
        MK8S(15)
#undef MK8R
#undef MK8L
#undef MK8S
#undef LB
#undef DECLA
#undef SLOADK
        // all 16 D-rows equal -> any reg holds the col value.
        // lane l's two output cols: colbase+l (group l>>4 = gq, c0..c3)
        // and colbase+64+l (group 4+gq, c4..c7); col-in-group = l&15 = n_.
        float v0 = c0[0];
        v0 = (gq == 1) ? c1[0] : v0;
        v0 = (gq == 2) ? c2[0] : v0;
        v0 = (gq == 3) ? c3[0] : v0;
        float v1 = c4[0];
        v1 = (gq == 1) ? c5[0] : v1;
        v1 = (gq == 2) ? c6[0] : v1;
        v1 = (gq == 3) ? c7[0] : v1;
        hbuf[nxt][colbase + lane] = f2h(tanh_fast(v0));
        hbuf[nxt][colbase + 64 + lane] = f2h(tanh_fast(v1));
        pv0 = pn0; pv1 = pn1; pv2 = pn2; pv3 = pn3;
        pv4 = pn4; pv5 = pn5; pv6 = pn6; pv7 = pn7;
        __syncthreads();
    }
    // final h lives in hbuf[0] (last write: t=1023 -> nxt=0)
    out[(long)B_ * O_ + (long)b * H_ + t_] = h2f_(hbuf[0][t_]);
    out[(long)B_ * O_ + (long)b * H_ + t_ + 256] = h2f_(hbuf[0][t_ + 256]);
    {                                               // o = h @ W_h2o^T + b_h2o
        float acc = bo[t_];
        const float4* wr = (const float4*)(Who + (long)t_ * H_);
        const u16* hb = hbuf[0];
#pragma unroll 4
        for (int k = 0; k < 128; ++k) {
            float4 wv = wr[k];
            acc += h2f_(hb[4 * k + 0]) * wv.x
                 + h2f_(hb[4 * k + 1]) * wv.y
                 + h2f_(hb[4 * k + 2]) * wv.z
                 + h2f_(hb[4 * k + 3]) * wv.w;
        }
        out[(long)b * O_ + t_] = acc;
    }
}

// ---------------------------------------------------------------------------
// Fallback (workspace too small): straightforward fp32, correct but slow.
// ---------------------------------------------------------------------------
__global__ __launch_bounds__(512) void k_fallback(const float* __restrict__ seq,
                                                  const float* __restrict__ W,
                                                  const float* __restrict__ bias,
                                                  const float* __restrict__ Who,
                                                  const float* __restrict__ bo,
                                                  float* __restrict__ out) {
    __shared__ float hb[2][H_];
    int b = blockIdx.x, j = threadIdx.x;
    const float* wrow = W + (long)j * IH_;
    float bj = bias[j];
    hb[0][j] = 0.f;
    __syncthreads();
    for (int t = 0; t < S_; ++t) {
        const float* x = seq + ((long)b * S_ + t) * I_;
        float acc = bj;
        for (int i = 0; i < I_; ++i) acc += x[i] * wrow[i];
        const float* hc = hb[t & 1];
        for (int k = 0; k < H_; ++k) acc += hc[k] * wrow[I_ + k];
        hb[(t & 1) ^ 1][j] = tanh_fast(acc);
        __syncthreads();
    }
    float hj = hb[0][j];
    out[(long)B_ * O_ + (long)b * H_ + j] = hj;
    if (j < O_) {
        float acc = bo[j];
        const float* wr = Who + (long)j * H_;
        for (int k = 0; k < H_; ++k) acc += hb[0][k] * wr[k];
        out[(long)b * O_ + j] = acc;
    }
}

extern "C" void kernel_launch(void* const* d_in, const int* in_sizes, int n_in,
                              void* d_out, int out_size, void* d_ws, size_t ws_size,
                              hipStream_t stream) {
    const float* seq = (const float*)d_in[0];   // (128,1024,256) fp32
    const float* W   = (const float*)d_in[1];   // (512,768) fp32
    const float* bi  = (const float*)d_in[2];   // (512,)
    const float* Who = (const float*)d_in[3];   // (256,512)
    const float* bo  = (const float*)d_in[4];   // (256,)
    float* out = (float*)d_out;                 // 32768 output + 65536 hidden

    const size_t WS_NEED = (size_t)PRE_OFF + (size_t)B_ * S_ * H_ * 2;

    if (ws_size >= WS_NEED) {
        char* ws = (char*)d_ws;
        uint4* wxb4 = (uint4*)(ws + WXB_OFF);
        uint4* whb4 = (uint4*)(ws + WHB_OFF);
        u16*   pre  = (u16*)(ws + PRE_OFF);
        k_convert<<<192, 256, 0, stream>>>(W, wxb4, whb4);
        k_phase1<<<2048, 256, 0, stream>>>(seq, wxb4, bi, pre);
        k_phase2<<<B_, 256, 0, stream>>>(pre, whb4, Who, bo, out);
    } else {
        k_fallback<<<B_, 512, 0, stream>>>(seq, W, bi, Who, bo, out);
    }
}

// Round 6
// 1642.280 us; speedup vs baseline: 2.4820x; 2.4820x over previous
//
#include <hip/hip_runtime.h>

typedef _Float16 h2f __attribute__((ext_vector_type(2)));
typedef _Float16 f16x8 __attribute__((ext_vector_type(8)));
typedef float f32x4 __attribute__((ext_vector_type(4)));
typedef unsigned int u32;
typedef unsigned short u16;

#define B_ 128
#define S_ 1024
#define I_ 256
#define H_ 512
#define O_ 256
#define IH_ 768

#if __has_builtin(__builtin_amdgcn_fdot2)
__device__ __forceinline__ float fdot2u(u32 a, u32 b, float c) {
    return __builtin_amdgcn_fdot2(__builtin_bit_cast(h2f, a),
                                  __builtin_bit_cast(h2f, b), c, false);
}
#else
__device__ __forceinline__ float fdot2u(u32 a, u32 b, float c) {
    h2f av = __builtin_bit_cast(h2f, a), bv = __builtin_bit_cast(h2f, b);
    return c + (float)av.x * (float)bv.x + (float)av.y * (float)bv.y;
}
#endif

__device__ __forceinline__ u32 pack2(float x, float y) {
    return __builtin_bit_cast(u32, __builtin_amdgcn_cvt_pkrtz(x, y));
}
__device__ __forceinline__ u16 f2h(float x) { return __builtin_bit_cast(u16, (_Float16)x); }
__device__ __forceinline__ float h2f_(u16 x) { return (float)__builtin_bit_cast(_Float16, x); }

__device__ __forceinline__ float tanh_fast(float x) {
    float e = __expf(-2.f * fabsf(x));     // e in (0,1] -- no overflow path
    float r = (1.f - e) / (1.f + e);
    return copysignf(r, x);
}

// MFMA: D = A(16x32)*B(32x16)+C, f16 in / f32 acc.
// Verified layouts (m89/m91): A[m=lane&15][k=(lane>>4)*8+j],
// B[k=(lane>>4)*8+j][n=lane&15], C/D col=lane&15 row=(lane>>4)*4+reg.
__device__ __forceinline__ f32x4 mfx(uint4 a, uint4 b, f32x4 c) {
    return __builtin_amdgcn_mfma_f32_16x16x32_f16(
        __builtin_bit_cast(f16x8, a), __builtin_bit_cast(f16x8, b), c, 0, 0, 0);
}
__device__ __forceinline__ f32x4 mf(uint4 a, const uint4* bp, f32x4 c) {
    uint4 b = *bp;
    return mfx(a, b, c);
}

#define REP8(X)  X(0) X(1) X(2) X(3) X(4) X(5) X(6) X(7)
#define REP16(X) REP8(X) X(8) X(9) X(10) X(11) X(12) X(13) X(14) X(15)
#define REPK12(X) X(0) X(1) X(2) X(3) X(4) X(5) X(6) X(7) X(8) X(9) X(10) X(11)

// ---------------------------------------------------------------------------
// Workspace layout (bytes):
//   wxb4 @ 0      : 16384 uint4 (256 KB)  Wx octets [q 0..31][col 0..511]
//                   octet q of col c = W[c][q*8 .. q*8+7] as f16
//   whb4 @ 256 KB : 32768 uint4 (512 KB)  Wh octets [q 0..63][n 0..511]
//                   octet q of col n = W[n][256+q*8 .. +7] as f16
//   pre  @ 1 MB   : 128*1024*512 f16 (128 MB)
// ---------------------------------------------------------------------------
#define WXB_OFF 0
#define WHB_OFF (256u << 10)
#define PRE_OFF (1u << 20)

__global__ __launch_bounds__(256) void k_convert(const float* __restrict__ W,
                                                 uint4* __restrict__ wxb4,
                                                 uint4* __restrict__ whb4) {
    int idx = blockIdx.x * 256 + threadIdx.x;       // 0..49151
    if (idx < 16384) {                               // wxb: q = idx>>9 (0..31)
        int q = idx >> 9, col = idx & 511;
        const float4* r = (const float4*)(W + (long)col * IH_ + q * 8);
        float4 u = r[0], v = r[1];
        wxb4[idx] = (uint4){pack2(u.x, u.y), pack2(u.z, u.w),
                            pack2(v.x, v.y), pack2(v.z, v.w)};
    } else {                                         // whb: q = 0..63
        int i2 = idx - 16384;
        int q = i2 >> 9, n = i2 & 511;
        const float4* r = (const float4*)(W + (long)n * IH_ + I_ + q * 8);
        float4 u = r[0], v = r[1];
        whb4[i2] = (uint4){pack2(u.x, u.y), pack2(u.z, u.w),
                           pack2(v.x, v.y), pack2(v.z, v.w)};
    }
}

// ---------------------------------------------------------------------------
// Phase 1 (MFMA GEMM, ~40 us -- unchanged):
// pre[r][j] = b_i2h[j] + sum_i x[r][i]*Wx[i][j], f16 out.
// ---------------------------------------------------------------------------
__global__ __launch_bounds__(256) __attribute__((amdgpu_waves_per_eu(2, 2)))
void k_phase1(const float* __restrict__ seq, const uint4* __restrict__ wxb4,
              const float* __restrict__ bias, u16* __restrict__ pre) {
    int w = threadIdx.x >> 6, l = threadIdx.x & 63;
    int lm = l & 15, lq = l >> 4;
    int mb_w = blockIdx.x * 64 + w * 16;
    long xrow = (long)(mb_w + lm) * I_;
#define DECLA1(k) uint4 a##k; { \
        const float4* xp = (const float4*)(seq + xrow + (k)*32 + lq*8); \
        float4 u = xp[0], v = xp[1]; \
        a##k = (uint4){pack2(u.x,u.y), pack2(u.z,u.w), pack2(v.x,v.y), pack2(v.z,v.w)}; }
    REP8(DECLA1)
#undef DECLA1
    int mrow0 = mb_w + lq * 4;
#pragma unroll
    for (int half = 0; half < 2; ++half) {
        int colbase = half * 256;
        const uint4* bptr = wxb4 + colbase + lm;
#define DECLC(n) float bv##n = bias[colbase + (n)*16 + lm]; \
                 f32x4 c##n = {bv##n, bv##n, bv##n, bv##n};
        REP16(DECLC)
#undef DECLC
#define ROW(k,n) c##n = mf(a##k, bptr + ((k)*4 + lq)*512 + (n)*16, c##n);
#define KS(k) ROW(k,0) ROW(k,1) ROW(k,2) ROW(k,3) ROW(k,4) ROW(k,5) ROW(k,6) ROW(k,7) \
              ROW(k,8) ROW(k,9) ROW(k,10) ROW(k,11) ROW(k,12) ROW(k,13) ROW(k,14) ROW(k,15)
        KS(0) KS(1) KS(2) KS(3) KS(4) KS(5) KS(6) KS(7)
#undef KS
#undef ROW
#define STN(n) { long cb = (long)colbase + (n)*16 + lm; \
        pre[(long)(mrow0+0)*H_ + cb] = f2h(c##n[0]); \
        pre[(long)(mrow0+1)*H_ + cb] = f2h(c##n[1]); \
        pre[(long)(mrow0+2)*H_ + cb] = f2h(c##n[2]); \
        pre[(long)(mrow0+3)*H_ + cb] = f2h(c##n[3]); }
        REP16(STN)
#undef STN
    }
}

// ---------------------------------------------------------------------------
// Phase 2 v6: v4 structure (512 thr = 8 waves = 2/SIMD -- the proven
// occupancy/register envelope) with the L2 stream ELIMINATED.
// Key accounting: Wh (512 KB) == CU regfile. v4 fed it as 320 KB regs +
// 128 KB LDS + 64 KB/step L2 stream (~1000 cyc/step on the 64 B/cyc L1
// pipe, the largest pipe term). But v4's 8 stream buffers (32 regs) were
// live across the whole step anyway -> promoting them to permanent
// resident fragments costs ZERO peak registers and deletes the stream:
//   K  0..11 : 48 resident uint4 (192 regs; same combined pressure as
//              v4's 40 resident + 8 stream bufs)
//   K 12..15 : LDS slabs q=48..63 (128 KB static, filled once)
//   streamed : none -- no vmcnt in the main loop at all.
// Broadcast-A MFMA recurrence otherwise identical to v4 (verified):
// A_K[m][k] = h[32K+k] for all m; D rows all equal = full 512-term dot.
// ---------------------------------------------------------------------------
__global__ __launch_bounds__(512) __attribute__((amdgpu_waves_per_eu(2, 2)))
void k_phase2(const u16* __restrict__ pre, const uint4* __restrict__ whb4,
              const float* __restrict__ Who, const float* __restrict__ bo,
              float* __restrict__ out) {
    __shared__ __align__(16) uint4 wlds[16 * 512];  // 128 KB, slabs q=48..63
    __shared__ __align__(16) u16 hbuf[2][H_];
    int b = blockIdx.x, j = threadIdx.x;
    int w = j >> 6, lane = j & 63;
    int n_ = lane & 15, gq = lane >> 4;             // col-in-group, k-subrow
    int colbase = w * 64;
    int cb0 = colbase, cb1 = colbase + 16, cb2 = colbase + 32, cb3 = colbase + 48;
    // resident B-fragments, K = 0..11 (48 x uint4 = 192 regs)
#define DECLB(K) \
    uint4 b##K##_0 = whb4[(4*(K) + gq) * 512 + cb0 + n_]; \
    uint4 b##K##_1 = whb4[(4*(K) + gq) * 512 + cb1 + n_]; \
    uint4 b##K##_2 = whb4[(4*(K) + gq) * 512 + cb2 + n_]; \
    uint4 b##K##_3 = whb4[(4*(K) + gq) * 512 + cb3 + n_];
    REPK12(DECLB)
#undef DECLB
#pragma unroll
    for (int s_ = 0; s_ < 16; ++s_) wlds[s_ * 512 + j] = whb4[(48 + s_) * 512 + j];
    // pre pointer: thread needs cols cb{g} + n_ each step (C-init values)
    const u16* pr = pre + (long)b * S_ * H_ + colbase + n_;
    hbuf[0][j] = 0;                                 // h_{-1} = 0
    __syncthreads();
    u16 pv0 = pr[0], pv1 = pr[16], pv2 = pr[32], pv3 = pr[48];
    for (int t = 0; t < S_; ++t) {
        int cur = t & 1, nxt = cur ^ 1;
        long tn = (t + 1 < S_) ? (long)(t + 1) : (long)t;
        int lz = 0;
        asm volatile("" : "+v"(lz));                // block LICM of LDS reads
        u16 pn0 = pr[tn * H_ +  0];                 // prefetch next step's pre
        u16 pn1 = pr[tn * H_ + 16];
        u16 pn2 = pr[tn * H_ + 32];
        u16 pn3 = pr[tn * H_ + 48];
        const u16* hc = hbuf[cur];
        // A-fragments: A_K = h[32K..32K+31] broadcast; lane reads 16B at
        // 64K + 16*gq bytes (uniform per 16-lane group -> LDS broadcast)
#define DECLA(K) uint4 a##K = *(const uint4*)(hc + 32*(K) + 8*gq);
        // LDS B-fragments, K = 12..15
#define LB(K) \
        uint4 l##K##_0 = wlds[(4*((K)-12) + gq) * 512 + cb0 + n_ + lz]; \
        uint4 l##K##_1 = wlds[(4*((K)-12) + gq) * 512 + cb1 + n_ + lz]; \
        uint4 l##K##_2 = wlds[(4*((K)-12) + gq) * 512 + cb2 + n_ + lz]; \
        uint4 l##K##_3 = wlds[(4*((K)-12) + gq) * 512 + cb3 + n_ + lz];
#define MK4(K, B0, B1, B2, B3) \
        c0 = mfx(a##K, B0, c0); c1 = mfx(a##K, B1, c1); \
        c2 = mfx(a##K, B2, c2); c3 = mfx(a##K, B3, c3);
        float p0f = h2f_(pv0), p1f = h2f_(pv1), p2f = h2f_(pv2), p3f = h2f_(pv3);
        f32x4 c0 = {p0f, p0f, p0f, p0f};
        f32x4 c1 = {p1f, p1f, p1f, p1f};
        f32x4 c2 = {p2f, p2f, p2f, p2f};
        f32x4 c3 = {p3f, p3f, p3f, p3f};
        DECLA(0) DECLA(1) DECLA(2) DECLA(3)
        MK4(0, b0_0, b0_1, b0_2, b0_3)
        MK4(1, b1_0, b1_1, b1_2, b1_3)
        MK4(2, b2_0, b2_1, b2_2, b2_3)
        DECLA(4) DECLA(5) DECLA(6) DECLA(7)
        MK4(3, b3_0, b3_1, b3_2, b3_3)
        MK4(4, b4_0, b4_1, b4_2, b4_3)
        LB(12)
        MK4(5, b5_0, b5_1, b5_2, b5_3)
        MK4(6, b6_0, b6_1, b6_2, b6_3)
        LB(13)
        DECLA(8) DECLA(9) DECLA(10) DECLA(11)
        MK4(7, b7_0, b7_1, b7_2, b7_3)
        MK4(8, b8_0, b8_1, b8_2, b8_3)
        LB(14)
        MK4(9, b9_0, b9_1, b9_2, b9_3)
        MK4(10, b10_0, b10_1, b10_2, b10_3)
        LB(15)
        DECLA(12) DECLA(13) DECLA(14) DECLA(15)
        MK4(11, b11_0, b11_1, b11_2, b11_3)
        MK4(12, l12_0, l12_1, l12_2, l12_3)
        MK4(13, l13_0, l13_1, l13_2, l13_3)
        MK4(14, l14_0, l14_1, l14_2, l14_3)
        MK4(15, l15_0, l15_1, l15_2, l15_3)
#undef MK4
#undef LB
#undef DECLA
        // all 16 D-rows equal -> any reg holds the col value; lane l's output
        // col = colbase + l -> group l>>4, col-in-group l&15
        float v = c0[0];
        v = (gq == 1) ? c1[0] : v;
        v = (gq == 2) ? c2[0] : v;
        v = (gq == 3) ? c3[0] : v;
        hbuf[nxt][colbase + lane] = f2h(tanh_fast(v));
        pv0 = pn0; pv1 = pn1; pv2 = pn2; pv3 = pn3;
        __syncthreads();
    }
    // final h lives in hbuf[0] (last write: t=1023 -> nxt=0)
    float hj = h2f_(hbuf[0][j]);
    out[(long)B_ * O_ + (long)b * H_ + j] = hj;     // hidden output
    if (j < O_) {                                   // o = h @ W_h2o^T + b_h2o
        float acc = bo[j];
        const float4* wr = (const float4*)(Who + (long)j * H_);
        const u16* hb = hbuf[0];
#pragma unroll 4
        for (int k = 0; k < 128; ++k) {
            float4 wv = wr[k];
            acc += h2f_(hb[4 * k + 0]) * wv.x
                 + h2f_(hb[4 * k + 1]) * wv.y
                 + h2f_(hb[4 * k + 2]) * wv.z
                 + h2f_(hb[4 * k + 3]) * wv.w;
        }
        out[(long)b * O_ + j] = acc;
    }
}

// ---------------------------------------------------------------------------
// Fallback (workspace too small): straightforward fp32, correct but slow.
// ---------------------------------------------------------------------------
__global__ __launch_bounds__(512) void k_fallback(const float* __restrict__ seq,
                                                  const float* __restrict__ W,
                                                  const float* __restrict__ bias,
                                                  const float* __restrict__ Who,
                                                  const float* __restrict__ bo,
                                                  float* __restrict__ out) {
    __shared__ float hb[2][H_];
    int b = blockIdx.x, j = threadIdx.x;
    const float* wrow = W + (long)j * IH_;
    float bj = bias[j];
    hb[0][j] = 0.f;
    __syncthreads();
    for (int t = 0; t < S_; ++t) {
        const float* x = seq + ((long)b * S_ + t) * I_;
        float acc = bj;
        for (int i = 0; i < I_; ++i) acc += x[i] * wrow[i];
        const float* hc = hb[t & 1];
        for (int k = 0; k < H_; ++k) acc += hc[k] * wrow[I_ + k];
        hb[(t & 1) ^ 1][j] = tanh_fast(acc);
        __syncthreads();
    }
    float hj = hb[0][j];
    out[(long)B_ * O_ + (long)b * H_ + j] = hj;
    if (j < O_) {
        float acc = bo[j];
        const float* wr = Who + (long)j * H_;
        for (int k = 0; k < H_; ++k) acc += hb[0][k] * wr[k];
        out[(long)b * O_ + j] = acc;
    }
}

extern "C" void kernel_launch(void* const* d_in, const int* in_sizes, int n_in,
                              void* d_out, int out_size, void* d_ws, size_t ws_size,
                              hipStream_t stream) {
    const float* seq = (const float*)d_in[0];   // (128,1024,256) fp32
    const float* W   = (const float*)d_in[1];   // (512,768) fp32
    const float* bi  = (const float*)d_in[2];   // (512,)
    const float* Who = (const float*)d_in[3];   // (256,512)
    const float* bo  = (const float*)d_in[4];   // (256,)
    float* out = (float*)d_out;                 // 32768 output + 65536 hidden

    const size_t WS_NEED = (size_t)PRE_OFF + (size_t)B_ * S_ * H_ * 2;

    if (ws_size >= WS_NEED) {
        char* ws = (char*)d_ws;
        uint4* wxb4 = (uint4*)(ws + WXB_OFF);
        uint4* whb4 = (uint4*)(ws + WHB_OFF);
        u16*   pre  = (u16*)(ws + PRE_OFF);
        k_convert<<<192, 256, 0, stream>>>(W, wxb4, whb4);
        k_phase1<<<2048, 256, 0, stream>>>(seq, wxb4, bi, pre);
        k_phase2<<<B_, 512, 0, stream>>>(pre, whb4, Who, bo, out);
    } else {
        k_fallback<<<B_, 512, 0, stream>>>(seq, W, bi, Who, bo, out);
    }
}